// Round 1
// baseline (357.768 us; speedup 1.0000x reference)
//
#include <hip/hip_runtime.h>

// LinearRTU: B=8 T=2048 D=1024 H=1024 R=128
// y (B,T,2H) fp32 + c1_last (B,H) + c2_last (B,H)
//
// ws layout: xu bf16 [16384][256]  @0        (8,388,608 B)
//            agg  float2 [8][128][1024] @8MiB  (8,388,608 B)
//            carries float2 [8][128][1024] @16MiB
// chunk length L=16, NC=128 chunks per (b,h)

using u16 = unsigned short;
using frag_ab = __attribute__((ext_vector_type(8))) short;   // 8 bf16
using frag_cd = __attribute__((ext_vector_type(4))) float;   // 4 fp32

__device__ __forceinline__ u16 f2bf(float f) {
    union { float f; unsigned u; } v; v.f = f;
    unsigned r = v.u + 0x7FFFu + ((v.u >> 16) & 1u);   // RNE
    return (u16)(r >> 16);
}
__device__ __forceinline__ float bf2f(u16 s) {
    union { unsigned u; float f; } v; v.u = ((unsigned)s) << 16;
    return v.f;
}
__device__ __forceinline__ frag_cd mfma16(frag_ab a, frag_ab b, frag_cd c) {
    return __builtin_amdgcn_mfma_f32_16x16x32_bf16(a, b, c, 0, 0, 0);
}

// ---------------- K1: xu[16384][256] = bf16( x[16384][1024] @ [U1|U2] ) ----------------
__global__ __launch_bounds__(256) void k1_gemm(
    const float* __restrict__ x, const float* __restrict__ U1,
    const float* __restrict__ U2, u16* __restrict__ xu)
{
    __shared__ __align__(16) u16 Alds[64 * 32];   // [m][k]
    __shared__ __align__(16) u16 Blds[64 * 32];   // [n][k] (transposed)
    const int tid = threadIdx.x;
    const int m0 = blockIdx.y * 64;               // grid.y = 256
    const int n0 = blockIdx.x * 64;               // grid.x = 4
    const float* Usrc = (n0 < 128) ? (U1 + n0) : (U2 + (n0 - 128));
    const int wave = tid >> 6, lane = tid & 63;
    const int wrow = wave >> 1, wcol = wave & 1;
    const int lm = lane & 15, kq = (lane >> 4) * 8;
    const int mA = tid >> 2, kbA = (tid & 3) * 8;      // A staging map
    const int nB = tid & 63, kgB = tid >> 6;           // B staging map
    frag_cd acc[2][2] = {};

    for (int k0 = 0; k0 < 1024; k0 += 32) {
        // stage A tile 64x32 (fp32 -> bf16), row-major [m][k]
        const float* xs = x + (size_t)(m0 + mA) * 1024 + k0 + kbA;
        float4 a0 = *(const float4*)xs;
        float4 a1 = *(const float4*)(xs + 4);
        u16 ap[8] = { f2bf(a0.x), f2bf(a0.y), f2bf(a0.z), f2bf(a0.w),
                      f2bf(a1.x), f2bf(a1.y), f2bf(a1.z), f2bf(a1.w) };
        *(frag_ab*)&Alds[mA * 32 + kbA] = *(frag_ab*)ap;
        // stage B tile 32x64 transposed -> [n][k]; global reads wave-coalesced over n
        u16 bp[8];
#pragma unroll
        for (int j = 0; j < 8; ++j)
            bp[j] = f2bf(Usrc[(size_t)(k0 + kgB * 8 + j) * 128 + nB]);
        *(frag_ab*)&Blds[nB * 32 + kgB * 8] = *(frag_ab*)bp;
        __syncthreads();

        frag_ab a0f = *(const frag_ab*)&Alds[(wrow * 32 + lm) * 32 + kq];
        frag_ab a1f = *(const frag_ab*)&Alds[(wrow * 32 + 16 + lm) * 32 + kq];
        frag_ab b0f = *(const frag_ab*)&Blds[(wcol * 32 + lm) * 32 + kq];
        frag_ab b1f = *(const frag_ab*)&Blds[(wcol * 32 + 16 + lm) * 32 + kq];
        acc[0][0] = mfma16(a0f, b0f, acc[0][0]);
        acc[0][1] = mfma16(a0f, b1f, acc[0][1]);
        acc[1][0] = mfma16(a1f, b0f, acc[1][0]);
        acc[1][1] = mfma16(a1f, b1f, acc[1][1]);
        __syncthreads();
    }
    // epilogue: D[row][col], row=(lane>>4)*4+i, col=lane&15
    const int rb = (lane >> 4) * 4;
#pragma unroll
    for (int fr = 0; fr < 2; ++fr)
#pragma unroll
        for (int fc = 0; fc < 2; ++fc)
#pragma unroll
            for (int i = 0; i < 4; ++i) {
                int m = m0 + wrow * 32 + fr * 16 + rb + i;
                int n = n0 + wcol * 32 + fc * 16 + lm;
                xu[(size_t)m * 256 + n] = f2bf(acc[fr][fc][i]);
            }
}

// ------------- shared helper: compute u1,u2 64x64 tiles into smem (bf16) -------------
// smem: 32768 u16 = 64 KiB.  [0..16383]: xu tile [64][256]; [16384..32767]: V [2][64][128]
// After MFMA, u tiles overwrite the first 8192 u16: u[br][t][h] = smem[br*4096 + t*64 + h]
__device__ __forceinline__ void compute_u_tile(
    const u16* __restrict__ xu, const float* __restrict__ V1,
    const float* __restrict__ V2, int t0, int h0, int tid, u16* smem)
{
    u16* xulds = smem;             // [64][256]
    u16* Vlds  = smem + 16384;     // [2][64][128] : br*8192 + n*128 + k
    const int wave = tid >> 6, lane = tid & 63;

    // stage xu rows [t0, t0+64) = contiguous 32 KiB -> LDS via global_load_lds (16B/lane)
    const char* gsrc = (const char*)xu + (size_t)t0 * 512;
    char* lbase = (char*)xulds;
#pragma unroll
    for (int i = 0; i < 8; ++i) {
        int blk = wave * 8 + i;    // 0..31, 1024 B each
        __builtin_amdgcn_global_load_lds(
            (const __attribute__((address_space(1))) void*)(gsrc + blk * 1024 + lane * 16),
            (__attribute__((address_space(3))) void*)(lbase + blk * 1024),
            16, 0, 0);
    }
    // stage V1/V2 slices [128][h0:h0+64] transposed -> [n][k] bf16
    const int nB = tid & 63, kg = tid >> 6;   // k = kg*32 + 0..31
#pragma unroll
    for (int br = 0; br < 2; ++br) {
        const float* Vsrc = br ? V2 : V1;
#pragma unroll
        for (int jj = 0; jj < 32; jj += 8) {
            u16 tmp[8];
#pragma unroll
            for (int j = 0; j < 8; ++j) {
                int k = kg * 32 + jj + j;
                tmp[j] = f2bf(Vsrc[(size_t)k * 1024 + h0 + nB]);
            }
            *(frag_ab*)&Vlds[br * 8192 + nB * 128 + kg * 32 + jj] = *(frag_ab*)tmp;
        }
    }
    __syncthreads();

    const int wrow = wave >> 1, wcol = wave & 1;
    const int lm = lane & 15, kq = (lane >> 4) * 8;
    frag_cd acc[2][2][2] = {};   // [br][fr][fc]
#pragma unroll
    for (int br = 0; br < 2; ++br)
#pragma unroll
        for (int ks = 0; ks < 4; ++ks) {
            frag_ab a0 = *(const frag_ab*)&xulds[(wrow * 32 + lm) * 256 + br * 128 + ks * 32 + kq];
            frag_ab a1 = *(const frag_ab*)&xulds[(wrow * 32 + 16 + lm) * 256 + br * 128 + ks * 32 + kq];
            frag_ab b0 = *(const frag_ab*)&Vlds[br * 8192 + (wcol * 32 + lm) * 128 + ks * 32 + kq];
            frag_ab b1 = *(const frag_ab*)&Vlds[br * 8192 + (wcol * 32 + 16 + lm) * 128 + ks * 32 + kq];
            acc[br][0][0] = mfma16(a0, b0, acc[br][0][0]);
            acc[br][0][1] = mfma16(a0, b1, acc[br][0][1]);
            acc[br][1][0] = mfma16(a1, b0, acc[br][1][0]);
            acc[br][1][1] = mfma16(a1, b1, acc[br][1][1]);
        }
    __syncthreads();   // everyone done reading xulds before overwrite
    const int rb = (lane >> 4) * 4;
#pragma unroll
    for (int br = 0; br < 2; ++br)
#pragma unroll
        for (int fr = 0; fr < 2; ++fr)
#pragma unroll
            for (int fc = 0; fc < 2; ++fc)
#pragma unroll
                for (int i = 0; i < 4; ++i) {
                    int tt = wrow * 32 + fr * 16 + rb + i;
                    int hh = wcol * 32 + fc * 16 + lm;
                    smem[br * 4096 + tt * 64 + hh] = f2bf(acc[br][fr][fc][i]);
                }
    __syncthreads();
}

__device__ __forceinline__ void lambda_of(const float* nu_log, const float* theta_log,
                                          int h, float& g, float& ph, float& gam)
{
    float rr = expf(-expf(nu_log[h]));
    float th = expf(theta_log[h]);
    g = rr * cosf(th);
    ph = rr * sinf(th);
    gam = sqrtf(fmaxf(1.0f - rr * rr, 0.0f));
}

// ---------------- K2: chunk aggregates (zero-init fold over each 16-step chunk) ----------------
__global__ __launch_bounds__(256) void k2_agg(
    const u16* __restrict__ xu, const float* __restrict__ V1, const float* __restrict__ V2,
    const float* __restrict__ nu_log, const float* __restrict__ theta_log,
    float2* __restrict__ agg)
{
    __shared__ __align__(16) u16 smem[32768];
    const int tid = threadIdx.x;
    const int h0 = blockIdx.x * 64;     // grid.x = 16
    const int t0 = blockIdx.y * 64;     // grid.y = 256 (global row in [0,16384))
    compute_u_tile(xu, V1, V2, t0, h0, tid, smem);

    const int hl = tid & 63, sc = tid >> 6;    // 4 sub-chunks of 16
    const int h = h0 + hl;
    float g, ph, gam;
    lambda_of(nu_log, theta_log, h, g, ph, gam);
    float bx = 0.f, by = 0.f;
#pragma unroll
    for (int j = 0; j < 16; ++j) {
        int tt = sc * 16 + j;
        float u1 = bf2f(smem[tt * 64 + hl]);
        float u2 = bf2f(smem[4096 + tt * 64 + hl]);
        float ex = gam * u1, ey = gam * u2;
        float nx = fmaf(g, bx, fmaf(-ph, by, ex));
        float ny = fmaf(ph, bx, fmaf(g, by, ey));
        bx = nx; by = ny;
    }
    const int b = t0 >> 11;
    const int tloc = t0 & 2047;
    const int nc = (tloc >> 4) + sc;
    agg[((size_t)b * 128 + nc) * 1024 + h] = make_float2(bx, by);
}

// ---------------- K3: scan across the 128 chunks per (b,h) ----------------
__global__ __launch_bounds__(256) void k3_scan(
    const float2* __restrict__ agg, const float* __restrict__ nu_log,
    const float* __restrict__ theta_log, const float* __restrict__ hc1,
    const float* __restrict__ hc2, float2* __restrict__ carries)
{
    const int idx = blockIdx.x * 256 + threadIdx.x;   // 0..8191
    const int b = idx >> 10, h = idx & 1023;
    float g, ph, gam;
    lambda_of(nu_log, theta_log, h, g, ph, gam);
    // A = lambda^16 by 4 complex squarings
    float ax = g, ay = ph;
#pragma unroll
    for (int i = 0; i < 4; ++i) { float nx = ax * ax - ay * ay, ny = 2.f * ax * ay; ax = nx; ay = ny; }
    float cx = hc1[idx], cy = hc2[idx];
    const float2* ap = agg + (size_t)b * 128 * 1024 + h;
    float2* cp = carries + (size_t)b * 128 * 1024 + h;
#pragma unroll 8
    for (int c = 0; c < 128; ++c) {
        cp[(size_t)c * 1024] = make_float2(cx, cy);
        float2 a = ap[(size_t)c * 1024];
        float nx = fmaf(ax, cx, fmaf(-ay, cy, a.x));
        float ny = fmaf(ay, cx, fmaf(ax, cy, a.y));
        cx = nx; cy = ny;
    }
}

// ---------------- K4: recompute u, apply carries, write y + finals ----------------
__global__ __launch_bounds__(256) void k4_apply(
    const u16* __restrict__ xu, const float* __restrict__ V1, const float* __restrict__ V2,
    const float* __restrict__ nu_log, const float* __restrict__ theta_log,
    const float2* __restrict__ carries, float* __restrict__ out)
{
    __shared__ __align__(16) u16 smem[32768];
    const int tid = threadIdx.x;
    const int h0 = blockIdx.x * 64;
    const int t0 = blockIdx.y * 64;
    compute_u_tile(xu, V1, V2, t0, h0, tid, smem);

    const int hl = tid & 63, sc = tid >> 6;
    const int h = h0 + hl;
    float g, ph, gam;
    lambda_of(nu_log, theta_log, h, g, ph, gam);
    const int b = t0 >> 11;
    const int tloc = t0 & 2047;
    const int nc = (tloc >> 4) + sc;
    float2 cin = carries[((size_t)b * 128 + nc) * 1024 + h];
    float cx = cin.x, cy = cin.y;
    float* yb = out + (size_t)b * (2048 * 2048);
#pragma unroll
    for (int j = 0; j < 16; ++j) {
        int tt = sc * 16 + j;
        float u1 = bf2f(smem[tt * 64 + hl]);
        float u2 = bf2f(smem[4096 + tt * 64 + hl]);
        float ex = gam * u1, ey = gam * u2;
        float nx = fmaf(g, cx, fmaf(-ph, cy, ex));
        float ny = fmaf(ph, cx, fmaf(g, cy, ey));
        cx = nx; cy = ny;
        int t = tloc + tt;
        yb[(size_t)t * 2048 + h] = cx;
        yb[(size_t)t * 2048 + 1024 + h] = cy;
    }
    if (tloc + sc * 16 == 2032) {    // this chunk ends at t = 2047
        out[(size_t)33554432 + (size_t)b * 1024 + h] = cx;
        out[(size_t)33554432 + 8192 + (size_t)b * 1024 + h] = cy;
    }
}

extern "C" void kernel_launch(void* const* d_in, const int* in_sizes, int n_in,
                              void* d_out, int out_size, void* d_ws, size_t ws_size,
                              hipStream_t stream) {
    const float* x         = (const float*)d_in[0];
    const float* nu_log    = (const float*)d_in[1];
    const float* theta_log = (const float*)d_in[2];
    const float* U1        = (const float*)d_in[3];
    const float* U2        = (const float*)d_in[4];
    const float* V1        = (const float*)d_in[5];
    const float* V2        = (const float*)d_in[6];
    const float* hc1       = (const float*)d_in[7];
    const float* hc2       = (const float*)d_in[8];

    u16*    xu      = (u16*)d_ws;                                   // 8 MiB
    float2* agg     = (float2*)((char*)d_ws + (size_t)8 * 1024 * 1024);   // 8 MiB
    float2* carries = (float2*)((char*)d_ws + (size_t)16 * 1024 * 1024);  // 8 MiB

    k1_gemm<<<dim3(4, 256), 256, 0, stream>>>(x, U1, U2, xu);
    k2_agg<<<dim3(16, 256), 256, 0, stream>>>(xu, V1, V2, nu_log, theta_log, agg);
    k3_scan<<<32, 256, 0, stream>>>(agg, nu_log, theta_log, hc1, hc2, carries);
    k4_apply<<<dim3(16, 256), 256, 0, stream>>>(xu, V1, V2, nu_log, theta_log, carries, (float*)d_out);
}

// Round 2
// 351.045 us; speedup vs baseline: 1.0192x; 1.0192x over previous
//
#include <hip/hip_runtime.h>

// LinearRTU: B=8 T=2048 D=1024 H=1024 R=128
// ws: xu bf16[16384][256] @0 (8MiB) | agg/carries float2[8][128][1024] @8MiB (8MiB)
//     Vt bf16[2][1024][128] @16MiB (512KiB) | Ubf bf16[256][1024] @16.5MiB (512KiB)

using u16 = unsigned short;
using frag_ab = __attribute__((ext_vector_type(8))) short;   // 8 bf16
using frag_cd = __attribute__((ext_vector_type(4))) float;   // 4 fp32

__device__ __forceinline__ u16 f2bf(float f) {
    union { float f; unsigned u; } v; v.f = f;
    unsigned r = v.u + 0x7FFFu + ((v.u >> 16) & 1u);   // RNE
    return (u16)(r >> 16);
}
__device__ __forceinline__ float bf2f(u16 s) {
    union { unsigned u; float f; } v; v.u = ((unsigned)s) << 16;
    return v.f;
}
__device__ __forceinline__ frag_cd mfma16(frag_ab a, frag_ab b, frag_cd c) {
    return __builtin_amdgcn_mfma_f32_16x16x32_bf16(a, b, c, 0, 0, 0);
}

// ------------- K0: pack U1|U2 -> Ubf [n=256][k=1024], V1/V2 -> Vt [2][h=1024][k=128] -------------
__global__ __launch_bounds__(256) void k0_pack(
    const float* __restrict__ U1, const float* __restrict__ U2,
    const float* __restrict__ V1, const float* __restrict__ V2,
    u16* __restrict__ Ubf, u16* __restrict__ Vt)
{
    int idx = blockIdx.x * 256 + threadIdx.x;    // grid 256 -> 65536 items
    if (idx < 32768) {
        int kg = idx & 127, n = idx >> 7;        // n 0..255
        const float* Us = (n < 128) ? U1 : U2;
        int col = n & 127;
        u16 tmp[8];
#pragma unroll
        for (int j = 0; j < 8; ++j)
            tmp[j] = f2bf(Us[(size_t)(kg * 8 + j) * 128 + col]);
        *(uint4*)&Ubf[(size_t)n * 1024 + kg * 8] = *(uint4*)tmp;
    } else {
        int i2 = idx - 32768;
        int kg = i2 & 15, h = (i2 >> 4) & 1023, br = i2 >> 14;
        const float* Vs = br ? V2 : V1;
        u16 tmp[8];
#pragma unroll
        for (int j = 0; j < 8; ++j)
            tmp[j] = f2bf(Vs[(size_t)(kg * 8 + j) * 1024 + h]);
        *(uint4*)&Vt[((size_t)br * 1024 + h) * 128 + kg * 8] = *(uint4*)tmp;
    }
}

// ------------- K1: xu[16384][256] = bf16( x @ [U1|U2] ), m-tile 32, full N=256 -------------
__global__ __launch_bounds__(256) void k1_gemm(
    const float* __restrict__ x, const u16* __restrict__ Ubf, u16* __restrict__ xu)
{
    __shared__ __align__(16) u16 Alds[32 * 32];    // row r: granule base 4r (mod 8 = 4-stagger, balanced)
    __shared__ __align__(16) u16 Blds[256 * 32];   // row N: +(N>>2) granule rotation
    const int tid = threadIdx.x;
    const int m0 = blockIdx.x * 32;                // grid 512
    const int wave = tid >> 6, lane = tid & 63;
    const int lm = lane & 15, q = lane >> 4;
    const int rowA = tid >> 2, kbA = (tid & 3) * 8;   // tid<128 stages A
    const int NB = tid;                               // thread = B row (0..255)
    frag_cd acc[2][4] = {};

    const float* xb = x + (size_t)(m0 + (rowA & 31)) * 1024 + kbA;
    const u16* ub = Ubf + (size_t)NB * 1024;

    float4 pA0 = {}, pA1 = {};
    uint4 pB[4];
    if (tid < 128) { pA0 = *(const float4*)xb; pA1 = *(const float4*)(xb + 4); }
#pragma unroll
    for (int g = 0; g < 4; ++g) pB[g] = *(const uint4*)(ub + g * 8);

    for (int k0 = 0; k0 < 1024; k0 += 32) {
        if (tid < 128) {
            u16 ap[8] = { f2bf(pA0.x), f2bf(pA0.y), f2bf(pA0.z), f2bf(pA0.w),
                          f2bf(pA1.x), f2bf(pA1.y), f2bf(pA1.z), f2bf(pA1.w) };
            *(uint4*)&Alds[rowA * 32 + kbA] = *(uint4*)ap;
        }
#pragma unroll
        for (int g = 0; g < 4; ++g)
            *(uint4*)&Blds[NB * 32 + ((g + (NB >> 2)) & 3) * 8] = pB[g];
        __syncthreads();
        if (k0 + 32 < 1024) {   // prefetch next tile (overlaps MFMA below)
            if (tid < 128) {
                pA0 = *(const float4*)(xb + k0 + 32);
                pA1 = *(const float4*)(xb + k0 + 36);
            }
#pragma unroll
            for (int g = 0; g < 4; ++g) pB[g] = *(const uint4*)(ub + k0 + 32 + g * 8);
        }
        frag_ab a[2], b[4];
#pragma unroll
        for (int m4 = 0; m4 < 2; ++m4)
            a[m4] = *(const frag_ab*)&Alds[(m4 * 16 + lm) * 32 + q * 8];
#pragma unroll
        for (int n4 = 0; n4 < 4; ++n4) {
            int N = wave * 64 + n4 * 16 + lm;
            b[n4] = *(const frag_ab*)&Blds[N * 32 + ((q + (N >> 2)) & 3) * 8];
        }
#pragma unroll
        for (int m4 = 0; m4 < 2; ++m4)
#pragma unroll
            for (int n4 = 0; n4 < 4; ++n4)
                acc[m4][n4] = mfma16(a[m4], b[n4], acc[m4][n4]);
        __syncthreads();
    }
    const int rb = q * 4;
#pragma unroll
    for (int m4 = 0; m4 < 2; ++m4)
#pragma unroll
        for (int n4 = 0; n4 < 4; ++n4)
#pragma unroll
            for (int i = 0; i < 4; ++i) {
                int m = m0 + m4 * 16 + rb + i;
                int n = wave * 64 + n4 * 16 + lm;
                xu[(size_t)m * 256 + n] = f2bf(acc[m4][n4][i]);
            }
}

// ------------- helper: u1,u2 64x64 tiles into smem (bank-conflict-free layouts) -------------
// smem u16[24832] (49664 B):
//   xulds [0,16640): row r at (r>>1)*520 + (r&1)*256 (2-row blocks padded to 1040 B for DMA)
//   Vlds  [16640,24832): [64][128], granule g stored at g^(n&15)
//   u overlays xulds after MFMA: u[br][tt][hl] at br*4352 + tt*68 + hl (stride-68 pad)
__device__ __forceinline__ void compute_u_tile(
    const u16* __restrict__ xu, const u16* __restrict__ Vt,
    int t0, int h0, int tid, u16* smem)
{
    u16* xulds = smem;
    u16* Vlds  = smem + 16640;
    const int wave = tid >> 6, lane = tid & 63;
    const int lm = lane & 15, q = lane >> 4;
    const int wrow = wave >> 1, wcol = wave & 1;

    // DMA xu rows [t0,t0+64): 32 source blocks of 1024 B -> LDS blocks of 1040 B
    const char* gsrc = (const char*)xu + (size_t)t0 * 512;
    char* lb = (char*)xulds;
#pragma unroll
    for (int i = 0; i < 8; ++i) {
        int blk = wave * 8 + i;
        __builtin_amdgcn_global_load_lds(
            (const __attribute__((address_space(1))) void*)(gsrc + blk * 1024 + lane * 16),
            (__attribute__((address_space(3))) void*)(lb + blk * 1040), 16, 0, 0);
    }

    const int nV = tid & 63, wV = tid >> 6;
    const int ra0 = wrow * 32 + lm, ra1 = ra0 + 16;
    const int ba0 = (ra0 >> 1) * 520 + (ra0 & 1) * 256;
    const int ba1 = (ra1 >> 1) * 520 + (ra1 & 1) * 256;
    const int nb0 = wcol * 32 + lm, nb1 = nb0 + 16;
    frag_cd acc[2][2][2] = {};
#pragma unroll
    for (int br = 0; br < 2; ++br) {
        // stage V[br] 64x128 bf16 from Vt (16B copies, XOR-swizzled granules)
#pragma unroll
        for (int ii = 0; ii < 4; ++ii) {
            int g = wV * 4 + ii;
            uint4 v = *(const uint4*)&Vt[((size_t)br * 1024 + h0 + nV) * 128 + g * 8];
            *(uint4*)&Vlds[nV * 128 + (g ^ (nV & 15)) * 8] = v;
        }
        __syncthreads();   // also drains xu DMA (vmcnt) on first pass
#pragma unroll
        for (int ks = 0; ks < 4; ++ks) {
            int koff = br * 128 + ks * 32 + q * 8;
            frag_ab a0 = *(const frag_ab*)&xulds[ba0 + koff];
            frag_ab a1 = *(const frag_ab*)&xulds[ba1 + koff];
            int gb = ks * 4 + q;
            frag_ab b0 = *(const frag_ab*)&Vlds[nb0 * 128 + (gb ^ (nb0 & 15)) * 8];
            frag_ab b1 = *(const frag_ab*)&Vlds[nb1 * 128 + (gb ^ (nb1 & 15)) * 8];
            acc[br][0][0] = mfma16(a0, b0, acc[br][0][0]);
            acc[br][0][1] = mfma16(a0, b1, acc[br][0][1]);
            acc[br][1][0] = mfma16(a1, b0, acc[br][1][0]);
            acc[br][1][1] = mfma16(a1, b1, acc[br][1][1]);
        }
        __syncthreads();   // done reading Vlds (br=0) / xulds (br=1)
    }
    const int rb = q * 4;
#pragma unroll
    for (int br = 0; br < 2; ++br)
#pragma unroll
        for (int fr = 0; fr < 2; ++fr)
#pragma unroll
            for (int fc = 0; fc < 2; ++fc)
#pragma unroll
                for (int i = 0; i < 4; ++i) {
                    int tt = wrow * 32 + fr * 16 + rb + i;
                    int hh = wcol * 32 + fc * 16 + lm;
                    smem[br * 4352 + tt * 68 + hh] = f2bf(acc[br][fr][fc][i]);
                }
    __syncthreads();
}

__device__ __forceinline__ void lambda_of(const float* nu_log, const float* theta_log,
                                          int h, float& g, float& ph, float& gam)
{
    float rr = expf(-expf(nu_log[h]));
    float th = expf(theta_log[h]);
    g = rr * cosf(th);
    ph = rr * sinf(th);
    gam = sqrtf(fmaxf(1.0f - rr * rr, 0.0f));
}

// ---------------- K2: per-chunk (L=16) aggregates ----------------
__global__ __launch_bounds__(256, 3) void k2_agg(
    const u16* __restrict__ xu, const u16* __restrict__ Vt,
    const float* __restrict__ nu_log, const float* __restrict__ theta_log,
    float2* __restrict__ agg)
{
    __shared__ __align__(16) u16 smem[24832];
    const int tid = threadIdx.x;
    const int h0 = blockIdx.x * 64;     // grid.x = 16
    const int t0 = blockIdx.y * 64;     // grid.y = 256
    compute_u_tile(xu, Vt, t0, h0, tid, smem);

    const int hl = tid & 63, sc = tid >> 6;
    const int h = h0 + hl;
    float g, ph, gam;
    lambda_of(nu_log, theta_log, h, g, ph, gam);
    float bx = 0.f, by = 0.f;
#pragma unroll
    for (int j = 0; j < 16; ++j) {
        int tt = sc * 16 + j;
        float u1 = bf2f(smem[tt * 68 + hl]);
        float u2 = bf2f(smem[4352 + tt * 68 + hl]);
        float ex = gam * u1, ey = gam * u2;
        float nx = fmaf(g, bx, fmaf(-ph, by, ex));
        float ny = fmaf(ph, bx, fmaf(g, by, ey));
        bx = nx; by = ny;
    }
    const int b = t0 >> 11;
    const int nc = ((t0 & 2047) >> 4) + sc;
    agg[((size_t)b * 128 + nc) * 1024 + h] = make_float2(bx, by);
}

// ---------------- K3: scan the 128 chunk aggregates per (b,h); in-place -> carries ----------------
__global__ __launch_bounds__(64) void k3_scan(
    float2* __restrict__ agg_carry, const float* __restrict__ nu_log,
    const float* __restrict__ theta_log, const float* __restrict__ hc1,
    const float* __restrict__ hc2)
{
    const int idx = blockIdx.x * 64 + threadIdx.x;   // 128 blocks x 64 = 8192
    const int b = idx >> 10, h = idx & 1023;
    float g, ph, gam;
    lambda_of(nu_log, theta_log, h, g, ph, gam);
    float ax = g, ay = ph;                            // lambda^16
#pragma unroll
    for (int i = 0; i < 4; ++i) { float nx = ax * ax - ay * ay, ny = 2.f * ax * ay; ax = nx; ay = ny; }
    float cx = hc1[idx], cy = hc2[idx];
    float2* acp = agg_carry + (size_t)b * 128 * 1024 + h;
#pragma unroll 8
    for (int c = 0; c < 128; ++c) {
        float2 a = acp[(size_t)c * 1024];            // load aggregate first,
        acp[(size_t)c * 1024] = make_float2(cx, cy); // then overwrite with entry carry
        float nx = fmaf(ax, cx, fmaf(-ay, cy, a.x));
        float ny = fmaf(ay, cx, fmaf(ax, cy, a.y));
        cx = nx; cy = ny;
    }
}

// ---------------- K4: recompute u, apply carries, write y + finals ----------------
__global__ __launch_bounds__(256, 3) void k4_apply(
    const u16* __restrict__ xu, const u16* __restrict__ Vt,
    const float* __restrict__ nu_log, const float* __restrict__ theta_log,
    const float2* __restrict__ carries, float* __restrict__ out)
{
    __shared__ __align__(16) u16 smem[24832];
    const int tid = threadIdx.x;
    const int h0 = blockIdx.x * 64;
    const int t0 = blockIdx.y * 64;
    compute_u_tile(xu, Vt, t0, h0, tid, smem);

    const int hl = tid & 63, sc = tid >> 6;
    const int h = h0 + hl;
    float g, ph, gam;
    lambda_of(nu_log, theta_log, h, g, ph, gam);
    const int b = t0 >> 11;
    const int tloc = t0 & 2047;
    const int nc = (tloc >> 4) + sc;
    float2 cin = carries[((size_t)b * 128 + nc) * 1024 + h];
    float cx = cin.x, cy = cin.y;
    float* yb = out + (size_t)b * (2048 * 2048);
#pragma unroll
    for (int j = 0; j < 16; ++j) {
        int tt = sc * 16 + j;
        float u1 = bf2f(smem[tt * 68 + hl]);
        float u2 = bf2f(smem[4352 + tt * 68 + hl]);
        float ex = gam * u1, ey = gam * u2;
        float nx = fmaf(g, cx, fmaf(-ph, cy, ex));
        float ny = fmaf(ph, cx, fmaf(g, cy, ey));
        cx = nx; cy = ny;
        int t = tloc + tt;
        yb[(size_t)t * 2048 + h] = cx;
        yb[(size_t)t * 2048 + 1024 + h] = cy;
    }
    if (tloc + sc * 16 == 2032) {
        out[(size_t)33554432 + (size_t)b * 1024 + h] = cx;
        out[(size_t)33554432 + 8192 + (size_t)b * 1024 + h] = cy;
    }
}

extern "C" void kernel_launch(void* const* d_in, const int* in_sizes, int n_in,
                              void* d_out, int out_size, void* d_ws, size_t ws_size,
                              hipStream_t stream) {
    const float* x         = (const float*)d_in[0];
    const float* nu_log    = (const float*)d_in[1];
    const float* theta_log = (const float*)d_in[2];
    const float* U1        = (const float*)d_in[3];
    const float* U2        = (const float*)d_in[4];
    const float* V1        = (const float*)d_in[5];
    const float* V2        = (const float*)d_in[6];
    const float* hc1       = (const float*)d_in[7];
    const float* hc2       = (const float*)d_in[8];

    u16*    xu  = (u16*)d_ws;
    float2* agg = (float2*)((char*)d_ws + (size_t)8 * 1024 * 1024);
    u16*    Vt  = (u16*)((char*)d_ws + (size_t)16 * 1024 * 1024);
    u16*    Ubf = (u16*)((char*)d_ws + (size_t)16 * 1024 * 1024 + 512 * 1024);

    k0_pack<<<256, 256, 0, stream>>>(U1, U2, V1, V2, Ubf, Vt);
    k1_gemm<<<512, 256, 0, stream>>>(x, Ubf, xu);
    k2_agg<<<dim3(16, 256), 256, 0, stream>>>(xu, Vt, nu_log, theta_log, agg);
    k3_scan<<<128, 64, 0, stream>>>(agg, nu_log, theta_log, hc1, hc2);
    k4_apply<<<dim3(16, 256), 256, 0, stream>>>(xu, Vt, nu_log, theta_log, agg, (float*)d_out);
}

// Round 3
// 277.319 us; speedup vs baseline: 1.2901x; 1.2659x over previous
//
#include <hip/hip_runtime.h>

// LinearRTU: B=8 T=2048 D=1024 H=1024 R=128
// ws: xu bf16[16384][256] @0 (8MiB) | agg/carries float2[8][128][1024] @8MiB (8MiB)
//     Vt bf16[2][1024][128] @16MiB (512KiB) | Ubfp bf16[16][256][64] @16.5MiB (512KiB)

using u16 = unsigned short;
using frag_ab = __attribute__((ext_vector_type(8))) short;   // 8 bf16
using frag_cd = __attribute__((ext_vector_type(4))) float;   // 4 fp32

__device__ __forceinline__ u16 f2bf(float f) {
    union { float f; unsigned u; } v; v.f = f;
    unsigned r = v.u + 0x7FFFu + ((v.u >> 16) & 1u);   // RNE
    return (u16)(r >> 16);
}
__device__ __forceinline__ float bf2f(u16 s) {
    union { unsigned u; float f; } v; v.u = ((unsigned)s) << 16;
    return v.f;
}
__device__ __forceinline__ frag_cd mfma16(frag_ab a, frag_ab b, frag_cd c) {
    return __builtin_amdgcn_mfma_f32_16x16x32_bf16(a, b, c, 0, 0, 0);
}

// ------------- K0: U1|U2 -> Ubfp [kt=16][n=256][64] ; V1/V2 -> Vt [2][h=1024][k=128] -------------
__global__ __launch_bounds__(256) void k0_pack(
    const float* __restrict__ U1, const float* __restrict__ U2,
    const float* __restrict__ V1, const float* __restrict__ V2,
    u16* __restrict__ Ubfp, u16* __restrict__ Vt)
{
    int idx = blockIdx.x * 256 + threadIdx.x;    // grid 256 -> 65536 items
    if (idx < 32768) {
        int kg = idx & 127, n = idx >> 7;        // n 0..255, k = kg*8..kg*8+7
        const float* Us = (n < 128) ? U1 : U2;
        int col = n & 127;
        u16 tmp[8];
#pragma unroll
        for (int j = 0; j < 8; ++j)
            tmp[j] = f2bf(Us[(size_t)(kg * 8 + j) * 128 + col]);
        // k-tile kt = kg>>3, within-tile k offset (kg&7)*8
        *(uint4*)&Ubfp[((size_t)(kg >> 3) * 256 + n) * 64 + (kg & 7) * 8] = *(uint4*)tmp;
    } else {
        int i2 = idx - 32768;
        int kg = i2 & 15, h = (i2 >> 4) & 1023, br = i2 >> 14;
        const float* Vs = br ? V2 : V1;
        u16 tmp[8];
#pragma unroll
        for (int j = 0; j < 8; ++j)
            tmp[j] = f2bf(Vs[(size_t)(kg * 8 + j) * 1024 + h]);
        *(uint4*)&Vt[((size_t)br * 1024 + h) * 128 + kg * 8] = *(uint4*)tmp;
    }
}

// ------------- K1: xu[16384][256] = bf16( x @ [U1|U2] ), m-tile 32, full N=256 -------------
// LDS row formula (both A and B): row r, k kk -> (r>>3)*520 + (r&7)*64 + kk
// (8-row DMA blocks padded to 1040 B; frag reads land <=2-way on banks = free)
__global__ __launch_bounds__(256) void k1_gemm(
    const float* __restrict__ x, const u16* __restrict__ Ubfp, u16* __restrict__ xu)
{
    __shared__ __align__(16) u16 Alds[4 * 520];    // 32 rows x 64 k (4160 B)
    __shared__ __align__(16) u16 Blds[32 * 520];   // 256 rows x 64 k (33280 B)
    u16* Tlds = Blds;                              // epilogue overlay (needs 16384 u16)
    const int tid = threadIdx.x;
    const int m0 = blockIdx.x * 32;                // grid 512
    const int wave = tid >> 6, lane = tid & 63;
    const int lm = lane & 15, q = lane >> 4;
    const int rowA = tid >> 3, kcA = tid & 7;      // A staging: 32 rows x 8 chunks
    frag_cd acc[2][4] = {};

    const float* xsrc = x + (size_t)(m0 + rowA) * 1024 + kcA * 8;
    const char* bsrc = (const char*)Ubfp;
    char* bdst = (char*)Blds;

    float4 pA0 = *(const float4*)xsrc;
    float4 pA1 = *(const float4*)(xsrc + 4);

    for (int kt = 0; kt < 16; ++kt) {
        // stage A (convert prefetched fp32 -> bf16), conflict-free swizzled rows
        {
            u16 ap[8] = { f2bf(pA0.x), f2bf(pA0.y), f2bf(pA0.z), f2bf(pA0.w),
                          f2bf(pA1.x), f2bf(pA1.y), f2bf(pA1.z), f2bf(pA1.w) };
            *(uint4*)&Alds[(rowA >> 3) * 520 + (rowA & 7) * 64 + kcA * 8] = *(uint4*)ap;
        }
        // stage B: contiguous 32 KB k-tile via 16-B global->LDS DMA
#pragma unroll
        for (int i = 0; i < 8; ++i) {
            int blk = wave * 8 + i;               // 32 blocks of 1024 B
            __builtin_amdgcn_global_load_lds(
                (const __attribute__((address_space(1))) void*)(bsrc + (size_t)kt * 32768 + blk * 1024 + lane * 16),
                (__attribute__((address_space(3))) void*)(bdst + blk * 1040), 16, 0, 0);
        }
        __syncthreads();
        if (kt + 1 < 16) {                        // prefetch next A tile (overlaps MFMA)
            pA0 = *(const float4*)(xsrc + (kt + 1) * 64);
            pA1 = *(const float4*)(xsrc + (kt + 1) * 64 + 4);
        }
        frag_ab a[2], b[4];
#pragma unroll
        for (int ksub = 0; ksub < 2; ++ksub) {
#pragma unroll
            for (int m4 = 0; m4 < 2; ++m4) {
                int ra = m4 * 16 + lm;
                a[m4] = *(const frag_ab*)&Alds[(ra >> 3) * 520 + (ra & 7) * 64 + ksub * 32 + q * 8];
            }
#pragma unroll
            for (int n4 = 0; n4 < 4; ++n4) {
                int nb = wave * 64 + n4 * 16 + lm;
                b[n4] = *(const frag_ab*)&Blds[(nb >> 3) * 520 + (nb & 7) * 64 + ksub * 32 + q * 8];
            }
#pragma unroll
            for (int m4 = 0; m4 < 2; ++m4)
#pragma unroll
                for (int n4 = 0; n4 < 4; ++n4)
                    acc[m4][n4] = mfma16(a[m4], b[n4], acc[m4][n4]);
        }
        __syncthreads();
    }
    // epilogue: acc -> Tlds[m 32][n 256] -> contiguous coalesced stores
    const int rb = q * 4;
#pragma unroll
    for (int m4 = 0; m4 < 2; ++m4)
#pragma unroll
        for (int n4 = 0; n4 < 4; ++n4)
#pragma unroll
            for (int i = 0; i < 4; ++i) {
                int m = m4 * 16 + rb + i;
                int n = wave * 64 + n4 * 16 + lm;
                Tlds[m * 256 + n] = f2bf(acc[m4][n4][i]);
            }
    __syncthreads();
#pragma unroll
    for (int p = 0; p < 4; ++p) {
        int m = p * 8 + (tid >> 5);
        int c = tid & 31;
        uint4 v = *(const uint4*)&Tlds[m * 256 + c * 8];
        *(uint4*)&xu[(size_t)(m0 + m) * 256 + c * 8] = v;
    }
}

// ------------- helper: u1,u2 64x64 tiles into smem (bank-conflict-free layouts) -------------
// smem u16[24832] (49664 B):
//   xulds [0,16640): row r at (r>>1)*520 + (r&1)*256 (2-row blocks padded to 1040 B for DMA)
//   Vlds  [16640,24832): [64][128], granule g stored at g^(n&15)
//   u overlays xulds after MFMA: u[br][tt][hl] at br*4352 + tt*68 + hl (stride-68 pad)
__device__ __forceinline__ void compute_u_tile(
    const u16* __restrict__ xu, const u16* __restrict__ Vt,
    int t0, int h0, int tid, u16* smem)
{
    u16* xulds = smem;
    u16* Vlds  = smem + 16640;
    const int wave = tid >> 6, lane = tid & 63;
    const int lm = lane & 15, q = lane >> 4;
    const int wrow = wave >> 1, wcol = wave & 1;

    // DMA xu rows [t0,t0+64): 32 source blocks of 1024 B -> LDS blocks of 1040 B
    const char* gsrc = (const char*)xu + (size_t)t0 * 512;
    char* lb = (char*)xulds;
#pragma unroll
    for (int i = 0; i < 8; ++i) {
        int blk = wave * 8 + i;
        __builtin_amdgcn_global_load_lds(
            (const __attribute__((address_space(1))) void*)(gsrc + blk * 1024 + lane * 16),
            (__attribute__((address_space(3))) void*)(lb + blk * 1040), 16, 0, 0);
    }

    const int nV = tid & 63, wV = tid >> 6;
    const int ra0 = wrow * 32 + lm, ra1 = ra0 + 16;
    const int ba0 = (ra0 >> 1) * 520 + (ra0 & 1) * 256;
    const int ba1 = (ra1 >> 1) * 520 + (ra1 & 1) * 256;
    const int nb0 = wcol * 32 + lm, nb1 = nb0 + 16;
    frag_cd acc[2][2][2] = {};
#pragma unroll
    for (int br = 0; br < 2; ++br) {
        // stage V[br] 64x128 bf16 from Vt (16B copies, XOR-swizzled granules)
#pragma unroll
        for (int ii = 0; ii < 4; ++ii) {
            int g = wV * 4 + ii;
            uint4 v = *(const uint4*)&Vt[((size_t)br * 1024 + h0 + nV) * 128 + g * 8];
            *(uint4*)&Vlds[nV * 128 + (g ^ (nV & 15)) * 8] = v;
        }
        __syncthreads();   // also drains xu DMA (vmcnt) on first pass
#pragma unroll
        for (int ks = 0; ks < 4; ++ks) {
            int koff = br * 128 + ks * 32 + q * 8;
            frag_ab a0 = *(const frag_ab*)&xulds[ba0 + koff];
            frag_ab a1 = *(const frag_ab*)&xulds[ba1 + koff];
            int gb = ks * 4 + q;
            frag_ab b0 = *(const frag_ab*)&Vlds[nb0 * 128 + (gb ^ (nb0 & 15)) * 8];
            frag_ab b1 = *(const frag_ab*)&Vlds[nb1 * 128 + (gb ^ (nb1 & 15)) * 8];
            acc[br][0][0] = mfma16(a0, b0, acc[br][0][0]);
            acc[br][0][1] = mfma16(a0, b1, acc[br][0][1]);
            acc[br][1][0] = mfma16(a1, b0, acc[br][1][0]);
            acc[br][1][1] = mfma16(a1, b1, acc[br][1][1]);
        }
        __syncthreads();   // done reading Vlds (br=0) / xulds (br=1)
    }
    const int rb = q * 4;
#pragma unroll
    for (int br = 0; br < 2; ++br)
#pragma unroll
        for (int fr = 0; fr < 2; ++fr)
#pragma unroll
            for (int fc = 0; fc < 2; ++fc)
#pragma unroll
                for (int i = 0; i < 4; ++i) {
                    int tt = wrow * 32 + fr * 16 + rb + i;
                    int hh = wcol * 32 + fc * 16 + lm;
                    smem[br * 4352 + tt * 68 + hh] = f2bf(acc[br][fr][fc][i]);
                }
    __syncthreads();
}

__device__ __forceinline__ void lambda_of(const float* nu_log, const float* theta_log,
                                          int h, float& g, float& ph, float& gam)
{
    float rr = expf(-expf(nu_log[h]));
    float th = expf(theta_log[h]);
    g = rr * cosf(th);
    ph = rr * sinf(th);
    gam = sqrtf(fmaxf(1.0f - rr * rr, 0.0f));
}

// ---------------- K2: per-chunk (L=16) aggregates ----------------
__global__ __launch_bounds__(256, 3) void k2_agg(
    const u16* __restrict__ xu, const u16* __restrict__ Vt,
    const float* __restrict__ nu_log, const float* __restrict__ theta_log,
    float2* __restrict__ agg)
{
    __shared__ __align__(16) u16 smem[24832];
    const int tid = threadIdx.x;
    const int h0 = blockIdx.x * 64;     // grid.x = 16
    const int t0 = blockIdx.y * 64;     // grid.y = 256
    compute_u_tile(xu, Vt, t0, h0, tid, smem);

    const int hl = tid & 63, sc = tid >> 6;
    const int h = h0 + hl;
    float g, ph, gam;
    lambda_of(nu_log, theta_log, h, g, ph, gam);
    float bx = 0.f, by = 0.f;
#pragma unroll
    for (int j = 0; j < 16; ++j) {
        int tt = sc * 16 + j;
        float u1 = bf2f(smem[tt * 68 + hl]);
        float u2 = bf2f(smem[4352 + tt * 68 + hl]);
        float ex = gam * u1, ey = gam * u2;
        float nx = fmaf(g, bx, fmaf(-ph, by, ex));
        float ny = fmaf(ph, bx, fmaf(g, by, ey));
        bx = nx; by = ny;
    }
    const int b = t0 >> 11;
    const int nc = ((t0 & 2047) >> 4) + sc;
    agg[((size_t)b * 128 + nc) * 1024 + h] = make_float2(bx, by);
}

// ---------------- K3: scan the 128 chunk aggregates per (b,h); in-place -> carries ----------------
__global__ __launch_bounds__(64) void k3_scan(
    float2* __restrict__ agg_carry, const float* __restrict__ nu_log,
    const float* __restrict__ theta_log, const float* __restrict__ hc1,
    const float* __restrict__ hc2)
{
    const int idx = blockIdx.x * 64 + threadIdx.x;   // 128 blocks x 64 = 8192
    const int b = idx >> 10, h = idx & 1023;
    float g, ph, gam;
    lambda_of(nu_log, theta_log, h, g, ph, gam);
    float ax = g, ay = ph;                            // lambda^16
#pragma unroll
    for (int i = 0; i < 4; ++i) { float nx = ax * ax - ay * ay, ny = 2.f * ax * ay; ax = nx; ay = ny; }
    float cx = hc1[idx], cy = hc2[idx];
    float2* acp = agg_carry + (size_t)b * 128 * 1024 + h;
#pragma unroll 8
    for (int c = 0; c < 128; ++c) {
        float2 a = acp[(size_t)c * 1024];            // load aggregate first,
        acp[(size_t)c * 1024] = make_float2(cx, cy); // then overwrite with entry carry
        float nx = fmaf(ax, cx, fmaf(-ay, cy, a.x));
        float ny = fmaf(ay, cx, fmaf(ax, cy, a.y));
        cx = nx; cy = ny;
    }
}

// ---------------- K4: recompute u, apply carries, write y + finals ----------------
__global__ __launch_bounds__(256, 3) void k4_apply(
    const u16* __restrict__ xu, const u16* __restrict__ Vt,
    const float* __restrict__ nu_log, const float* __restrict__ theta_log,
    const float2* __restrict__ carries, float* __restrict__ out)
{
    __shared__ __align__(16) u16 smem[24832];
    const int tid = threadIdx.x;
    const int h0 = blockIdx.x * 64;
    const int t0 = blockIdx.y * 64;
    compute_u_tile(xu, Vt, t0, h0, tid, smem);

    const int hl = tid & 63, sc = tid >> 6;
    const int h = h0 + hl;
    float g, ph, gam;
    lambda_of(nu_log, theta_log, h, g, ph, gam);
    const int b = t0 >> 11;
    const int tloc = t0 & 2047;
    const int nc = (tloc >> 4) + sc;
    float2 cin = carries[((size_t)b * 128 + nc) * 1024 + h];
    float cx = cin.x, cy = cin.y;
    float* yb = out + (size_t)b * (2048 * 2048);
#pragma unroll
    for (int j = 0; j < 16; ++j) {
        int tt = sc * 16 + j;
        float u1 = bf2f(smem[tt * 68 + hl]);
        float u2 = bf2f(smem[4352 + tt * 68 + hl]);
        float ex = gam * u1, ey = gam * u2;
        float nx = fmaf(g, cx, fmaf(-ph, cy, ex));
        float ny = fmaf(ph, cx, fmaf(g, cy, ey));
        cx = nx; cy = ny;
        int t = tloc + tt;
        yb[(size_t)t * 2048 + h] = cx;
        yb[(size_t)t * 2048 + 1024 + h] = cy;
    }
    if (tloc + sc * 16 == 2032) {
        out[(size_t)33554432 + (size_t)b * 1024 + h] = cx;
        out[(size_t)33554432 + 8192 + (size_t)b * 1024 + h] = cy;
    }
}

extern "C" void kernel_launch(void* const* d_in, const int* in_sizes, int n_in,
                              void* d_out, int out_size, void* d_ws, size_t ws_size,
                              hipStream_t stream) {
    const float* x         = (const float*)d_in[0];
    const float* nu_log    = (const float*)d_in[1];
    const float* theta_log = (const float*)d_in[2];
    const float* U1        = (const float*)d_in[3];
    const float* U2        = (const float*)d_in[4];
    const float* V1        = (const float*)d_in[5];
    const float* V2        = (const float*)d_in[6];
    const float* hc1       = (const float*)d_in[7];
    const float* hc2       = (const float*)d_in[8];

    u16*    xu   = (u16*)d_ws;
    float2* agg  = (float2*)((char*)d_ws + (size_t)8 * 1024 * 1024);
    u16*    Vt   = (u16*)((char*)d_ws + (size_t)16 * 1024 * 1024);
    u16*    Ubfp = (u16*)((char*)d_ws + (size_t)16 * 1024 * 1024 + 512 * 1024);

    k0_pack<<<256, 256, 0, stream>>>(U1, U2, V1, V2, Ubfp, Vt);
    k1_gemm<<<512, 256, 0, stream>>>(x, Ubfp, xu);
    k2_agg<<<dim3(16, 256), 256, 0, stream>>>(xu, Vt, nu_log, theta_log, agg);
    k3_scan<<<128, 64, 0, stream>>>(agg, nu_log, theta_log, hc1, hc2);
    k4_apply<<<dim3(16, 256), 256, 0, stream>>>(xu, Vt, nu_log, theta_log, agg, (float*)d_out);
}